// Round 7
// baseline (545.591 us; speedup 1.0000x reference)
//
#include <hip/hip_runtime.h>
#include <hip/hip_bf16.h>

#define N0_  320000
#define N1_  80000
#define N2_  16000
#define INC_ 128
#define HID_ 64
#define H1_  4
#define C1_  256   // H1*HID
#define OUT_ 48
#define OUTP_ 64   // padded layer-2 feature stride
#define NEG_ 0.2f

typedef __attribute__((ext_vector_type(8))) short bfrag8;   // 8 bf16 (4 VGPRs)
typedef __attribute__((ext_vector_type(4))) float ffrag4;   // 4 fp32 acc

__device__ __forceinline__ float bf2f(unsigned short u){
  unsigned int v = ((unsigned int)u) << 16;
  return __uint_as_float(v);
}
__device__ __forceinline__ unsigned short f2bf(float f){
  unsigned int u = __float_as_uint(f);
  u += 0x7FFFu + ((u >> 16) & 1u);   // round-to-nearest-even
  return (unsigned short)(u >> 16);
}
__device__ __forceinline__ void unpack2(unsigned int u, float& lo, float& hi){
  lo = __uint_as_float(u << 16);
  hi = __uint_as_float(u & 0xffff0000u);
}

// ---- all 4 weight transposes in one kernel (f32 [K][N] -> bf16 [N][K]) ----
__global__ void transpose_all(const float* __restrict__ Wl1, const float* __restrict__ Wr1,
                              const float* __restrict__ Wl2, const float* __restrict__ Wr2,
                              unsigned short* __restrict__ Wt1l, unsigned short* __restrict__ Wt1r,
                              unsigned short* __restrict__ Wt2l, unsigned short* __restrict__ Wt2r){
  int idx = blockIdx.x*256 + threadIdx.x;
  if (idx < 32768){ int n = idx >> 7, k = idx & 127; Wt1l[idx] = f2bf(Wl1[k*C1_ + n]); }
  else if (idx < 65536){ int j = idx - 32768; int n = j >> 7, k = j & 127; Wt1r[j] = f2bf(Wr1[k*C1_ + n]); }
  else if (idx < 77824){ int j = idx - 65536; int n = j >> 8, k = j & 255; Wt2l[j] = f2bf(Wl2[k*OUT_ + n]); }
  else if (idx < 90112){ int j = idx - 77824; int n = j >> 8, k = j & 255; Wt2r[j] = f2bf(Wr2[k*OUT_ + n]); }
}

// ------- GEMM1 grid-split: blocks [0,nblk_l) -> Wl/outl, rest -> Wr/outr -------
// 64 rows/block. One 17.4KB LDS buffer aliases A-tile (64x136) and C-bounce (32x264 halves).
// ks-outer K-loop holds only 4 B-frags live -> low VGPR, 4 blocks/CU.
__global__ __launch_bounds__(256, 4) void gemm1_split(
    const float* __restrict__ X,
    const unsigned short* __restrict__ Wtl, const unsigned short* __restrict__ Wtr,
    const float* __restrict__ bl, const float* __restrict__ br,
    unsigned short* __restrict__ outl, unsigned short* __restrict__ outr, int nblk_l)
{
  __shared__ unsigned short Buf[8704];    // As[64][136] (17408B) / Cs-half[32][264] (16896B)
  const int t = threadIdx.x;
  const int lane = t & 63, wave = t >> 6;
  const bool isR = (int)blockIdx.x >= nblk_l;
  const int row0 = (isR ? (int)blockIdx.x - nblk_l : (int)blockIdx.x) << 6;
  const unsigned short* Wt = isR ? Wtr : Wtl;
  const float* bias = isR ? br : bl;
  unsigned short* out = isR ? outr : outl;
  const int l15 = lane & 15, q = lane >> 4;
  const int wcol = wave << 6;
  const int c4 = t & 31;

  // stage A tile: 64 rows x 128 k, f32 -> bf16
  #pragma unroll
  for (int i = 0; i < 8; ++i){
    int r = (i<<3) + (t>>5);
    float4 xv = *(const float4*)(X + ((size_t)(row0 + r) << 7) + (c4<<2));
    ushort4 s; s.x=f2bf(xv.x); s.y=f2bf(xv.y); s.z=f2bf(xv.z); s.w=f2bf(xv.w);
    *(ushort4*)(&Buf[r*136 + (c4<<2)]) = s;
  }
  __syncthreads();

  ffrag4 z = {0.f, 0.f, 0.f, 0.f};
  ffrag4 acc[4][4];
  #pragma unroll
  for (int mt = 0; mt < 4; ++mt)
    #pragma unroll
    for (int nt = 0; nt < 4; ++nt) acc[mt][nt] = z;

  #pragma unroll
  for (int ks = 0; ks < 4; ++ks){
    bfrag8 bfr[4];
    #pragma unroll
    for (int nt = 0; nt < 4; ++nt)
      bfr[nt] = *(const bfrag8*)(Wt + (size_t)(wcol + (nt<<4) + l15)*128 + (ks<<5) + (q<<3));
    #pragma unroll
    for (int mt = 0; mt < 4; ++mt){
      bfrag8 af = *(const bfrag8*)(&Buf[((mt<<4) + l15)*136 + (ks<<5) + (q<<3)]);
      #pragma unroll
      for (int nt = 0; nt < 4; ++nt)
        acc[mt][nt] = __builtin_amdgcn_mfma_f32_16x16x32_bf16(af, bfr[nt], acc[mt][nt], 0, 0, 0);
    }
  }

  float bb[4];
  #pragma unroll
  for (int nt = 0; nt < 4; ++nt) bb[nt] = bias[wcol + (nt<<4) + l15];

  // epilogue in two 32-row halves through the aliased buffer
  #pragma unroll
  for (int h = 0; h < 2; ++h){
    __syncthreads();                       // prior Buf reads (A-tile or half 0) complete
    #pragma unroll
    for (int mh = 0; mh < 2; ++mh){
      int mt = (h<<1) + mh;
      #pragma unroll
      for (int nt = 0; nt < 4; ++nt)
        #pragma unroll
        for (int rg = 0; rg < 4; ++rg)
          Buf[((mh<<4) + (q<<2) + rg)*264 + wcol + (nt<<4) + l15] = f2bf(acc[mt][nt][rg] + bb[nt]);
    }
    __syncthreads();
    #pragma unroll
    for (int i = 0; i < 4; ++i){
      int idx = (i<<8) + t;                // 1024 chunks of 8 bf16 (32 rows x 256)
      int r = idx >> 5, c = (idx & 31) << 3;
      *(bfrag8*)(out + ((size_t)(row0 + (h<<5) + r) << 8) + c) = *(const bfrag8*)(&Buf[r*264 + c]);
    }
  }
}

// ------- GEMM2 grid-split: [M,256] bf16 @ Wt2[48][256] + b -> f32 [M][64] zero-padded -------
// wave = n-tile (0..2 real cols, wave 3 writes pad); B-frags in registers from L2.
__global__ __launch_bounds__(256, 4) void gemm2_split(
    const unsigned short* __restrict__ Hin,
    const unsigned short* __restrict__ Wtl, const unsigned short* __restrict__ Wtr,
    const float* __restrict__ bl, const float* __restrict__ br,
    float* __restrict__ outl, float* __restrict__ outr, int nblk_l)
{
  __shared__ unsigned short As2[64*264];   // 33792 B
  const int t = threadIdx.x;
  const int lane = t & 63, wave = t >> 6;
  const bool isR = (int)blockIdx.x >= nblk_l;
  const int row0 = (isR ? (int)blockIdx.x - nblk_l : (int)blockIdx.x) << 6;
  const unsigned short* Wt = isR ? Wtr : Wtl;
  const float* bias = isR ? br : bl;
  float* out = isR ? outr : outl;
  const int l15 = lane & 15, q = lane >> 4;

  #pragma unroll
  for (int i = 0; i < 8; ++i){
    int idx = (i<<8) + t;                  // 2048 chunks (64 rows x 256 cols)
    int r = idx >> 5, c = (idx & 31) << 3;
    *(bfrag8*)(&As2[r*264 + c]) = *(const bfrag8*)(Hin + ((size_t)(row0 + r) << 8) + c);
  }
  __syncthreads();

  if (wave < 3){
    bfrag8 bfr[8];
    #pragma unroll
    for (int ks = 0; ks < 8; ++ks)
      bfr[ks] = *(const bfrag8*)(Wt + (size_t)((wave<<4) + l15)*256 + (ks<<5) + (q<<3));
    ffrag4 z = {0.f, 0.f, 0.f, 0.f};
    ffrag4 acc[4] = {z, z, z, z};
    #pragma unroll
    for (int ks = 0; ks < 8; ++ks){
      #pragma unroll
      for (int mt = 0; mt < 4; ++mt){
        bfrag8 af = *(const bfrag8*)(&As2[((mt<<4) + l15)*264 + (ks<<5) + (q<<3)]);
        acc[mt] = __builtin_amdgcn_mfma_f32_16x16x32_bf16(af, bfr[ks], acc[mt], 0, 0, 0);
      }
    }
    int col = (wave<<4) + l15;
    float bb = bias[col];
    #pragma unroll
    for (int mt = 0; mt < 4; ++mt)
      #pragma unroll
      for (int rg = 0; rg < 4; ++rg){
        int row = row0 + (mt<<4) + (q<<2) + rg;
        out[(size_t)row*OUTP_ + col] = acc[mt][rg] + bb;
      }
  } else {
    #pragma unroll
    for (int i = 0; i < 16; ++i){          // zero pad cols 48..63, all 64 rows
      int row = row0 + (i<<2) + q;
      out[(size_t)row*OUTP_ + 48 + l15] = 0.f;
    }
  }
}

// ---------------- CSR build (both edge sets per kernel) ----------------
__global__ void hist_both(const int* __restrict__ dst1, const int* __restrict__ dst2,
                          int* __restrict__ cnt1, int* __restrict__ cnt2, int E1, int E2){
  int i = blockIdx.x*256 + threadIdx.x;
  if (i < E1) atomicAdd(&cnt1[dst1[i]], 1);
  else if (i < E1 + E2) atomicAdd(&cnt2[dst2[i - E1]], 1);
}

__global__ __launch_bounds__(256) void scan_local_both(
    const int* __restrict__ in1, const int* __restrict__ in2,
    int* __restrict__ ex1, int* __restrict__ ex2,
    int* __restrict__ part1, int* __restrict__ part2, int n1, int n2, int nb1){
  __shared__ int s[256];
  const int* in; int* excl; int* partials; int n; int b;
  if ((int)blockIdx.x < nb1){ in = in1; excl = ex1; partials = part1; n = n1; b = blockIdx.x; }
  else { in = in2; excl = ex2; partials = part2; n = n2; b = blockIdx.x - nb1; }
  int t = threadIdx.x, i = b*256 + t;
  int v = (i < n) ? in[i] : 0;
  s[t] = v; __syncthreads();
  #pragma unroll
  for (int off = 1; off < 256; off <<= 1){
    int u = (t >= off) ? s[t-off] : 0;
    __syncthreads();
    s[t] += u; __syncthreads();
  }
  if (i < n) excl[i] = s[t] - v;
  if (t == 255) partials[b] = s[255];
}

__global__ __launch_bounds__(512) void scan_partials_both(
    int* __restrict__ part1, int* __restrict__ part2, int nb1, int nb2){
  __shared__ int s[512];
  int* partials = blockIdx.x ? part2 : part1;
  int nb = blockIdx.x ? nb2 : nb1;
  int t = threadIdx.x;
  int v = (t < nb) ? partials[t] : 0;
  s[t] = v; __syncthreads();
  #pragma unroll
  for (int off = 1; off < 512; off <<= 1){
    int u = (t >= off) ? s[t-off] : 0;
    __syncthreads();
    s[t] += u; __syncthreads();
  }
  if (t < nb) partials[t] = s[t] - v;
}

__global__ void scan_finalize_both(
    int* __restrict__ ex1, int* __restrict__ ex2,
    const int* __restrict__ part1, const int* __restrict__ part2,
    int* __restrict__ cur1, int* __restrict__ cur2, int n1, int n2, int nb1){
  int* excl; const int* partials; int* cursor; int n; int b;
  if ((int)blockIdx.x < nb1){ excl = ex1; partials = part1; cursor = cur1; n = n1; b = blockIdx.x; }
  else { excl = ex2; partials = part2; cursor = cur2; n = n2; b = blockIdx.x - nb1; }
  int i = b*256 + threadIdx.x;
  if (i >= n) return;
  int o = excl[i] + partials[b];
  excl[i] = o; cursor[i] = o;
}

__global__ void scatter_both(const int* __restrict__ src1, const int* __restrict__ dst1,
                             const int* __restrict__ src2, const int* __restrict__ dst2,
                             int* __restrict__ cur1, int* __restrict__ cur2,
                             int* __restrict__ perm1, int* __restrict__ perm2, int E1, int E2){
  int i = blockIdx.x*256 + threadIdx.x;
  if (i < E1){
    int pos = atomicAdd(&cur1[dst1[i]], 1);
    perm1[pos] = src1[i];
  } else if (i < E1 + E2){
    int j = i - E1;
    int pos = atomicAdd(&cur2[dst2[j]], 1);
    perm2[pos] = src2[j];
  }
}

// ---------- fused layer-1 aggregation: wave/node, 2 edges/iter, 1-ahead gather prefetch ----------
__global__ __launch_bounds__(256) void gat_aggregate1(
    const unsigned short* __restrict__ xl, const unsigned short* __restrict__ xr,
    const int* __restrict__ offsets, const int* __restrict__ counts,
    const int* __restrict__ perm, const float* __restrict__ att,
    const float* __restrict__ bias, unsigned short* __restrict__ hout, int n)
{
  int node = (blockIdx.x << 2) + (threadIdx.x >> 6);
  if (node >= n) return;
  const int lane = threadIdx.x & 63;
  const int slot = lane >> 5;          // edge parity
  const int sub  = lane & 31;
  const int elem = sub << 3;           // 8 channels per lane (head = sub>>3)
  const unsigned int ebyte = (unsigned)elem << 1;
  const char* xlb = (const char*)xl;

  const int st = offsets[node], cnt = counts[node];
  uint4 ru = *(const uint4*)(xr + ((size_t)node << 8) + elem);
  float r[8];
  unpack2(ru.x, r[0], r[1]); unpack2(ru.y, r[2], r[3]);
  unpack2(ru.z, r[4], r[5]); unpack2(ru.w, r[6], r[7]);
  float4 al = *(const float4*)(att + elem);
  float4 ah = *(const float4*)(att + elem + 4);
  float a[8] = {al.x, al.y, al.z, al.w, ah.x, ah.y, ah.z, ah.w};

  float acc[8] = {0,0,0,0,0,0,0,0};
  float den = 0.f;

  for (int jb = 0; jb < cnt; jb += 64){
    int m = cnt - jb; if (m > 64) m = 64;
    int pv = (lane < m) ? perm[st + jb + lane] : 0;
    int s_cur = __shfl(pv, slot);
    uint4 xc = *(const uint4*)(xlb + (((unsigned)s_cur << 9) + ebyte));
    for (int j = 0; j < m; j += 2){
      int s_next = __shfl(pv, (j + 2 + slot) & 63);     // out-of-range -> pv=0 lanes (safe)
      uint4 xn = *(const uint4*)(xlb + (((unsigned)s_next << 9) + ebyte));  // prefetch j+2
      float x[8];
      unpack2(xc.x, x[0], x[1]); unpack2(xc.y, x[2], x[3]);
      unpack2(xc.z, x[4], x[5]); unpack2(xc.w, x[6], x[7]);
      float p = 0.f;
      #pragma unroll
      for (int i = 0; i < 8; ++i){
        float v = x[i] + r[i];
        float e = fmaf(NEG_, fminf(v, 0.f), fmaxf(v, 0.f));
        p = fmaf(e, a[i], p);
      }
      p += __shfl_xor(p, 1);
      p += __shfl_xor(p, 2);
      p += __shfl_xor(p, 4);         // full 64-ch head dot on all 8 lanes
      float ex = __expf(p);          // |alpha| bounded -> native exp safe
      ex = (j + slot < m) ? ex : 0.f;
      den += ex;
      #pragma unroll
      for (int i = 0; i < 8; ++i) acc[i] = fmaf(ex, x[i], acc[i]);
      xc = xn;
    }
  }
  den += __shfl_xor(den, 32);
  #pragma unroll
  for (int i = 0; i < 8; ++i) acc[i] += __shfl_xor(acc[i], 32);

  if (slot == 0){
    float w = 1.f / (den + 1e-16f);
    float4 bl = *(const float4*)(bias + elem);
    float4 bh = *(const float4*)(bias + elem + 4);
    float b[8] = {bl.x, bl.y, bl.z, bl.w, bh.x, bh.y, bh.z, bh.w};
    unsigned int o[4];
    #pragma unroll
    for (int i = 0; i < 4; ++i){
      unsigned short lo = f2bf(fmaxf(fmaf(acc[2*i],   w, b[2*i]),   0.f));
      unsigned short hi = f2bf(fmaxf(fmaf(acc[2*i+1], w, b[2*i+1]), 0.f));
      o[i] = (unsigned)lo | ((unsigned)hi << 16);
    }
    *(uint4*)(hout + ((size_t)node << 8) + elem) = make_uint4(o[0], o[1], o[2], o[3]);
  }
}

// ---------- fused layer-2 aggregation + log_softmax: wave/node, 4 edges/iter, prefetch ----------
__global__ __launch_bounds__(256) void gat_aggregate2(
    const float* __restrict__ xl, const float* __restrict__ xr,   // padded [.,64]
    const int* __restrict__ offsets, const int* __restrict__ counts,
    const int* __restrict__ perm, const float* __restrict__ att,
    const float* __restrict__ bias, float* __restrict__ out, int n)
{
  int node = (blockIdx.x << 2) + (threadIdx.x >> 6);
  if (node >= n) return;
  const int lane = threadIdx.x & 63;
  const int slot = lane >> 4;          // 0..3
  const int sub  = lane & 15;          // 4 channels (pad beyond 48)
  const bool realc = sub < 12;

  const int st = offsets[node], cnt = counts[node];
  float4 r = *(const float4*)(xr + (size_t)node*OUTP_ + (sub<<2));   // pads are 0
  float4 a = realc ? *(const float4*)(att + (sub<<2)) : make_float4(0,0,0,0);
  float4 acc = make_float4(0,0,0,0);
  float den = 0.f;

  for (int jb = 0; jb < cnt; jb += 64){
    int m = cnt - jb; if (m > 64) m = 64;
    int pv = (lane < m) ? perm[st + jb + lane] : 0;
    int s_cur = __shfl(pv, slot);
    float4 xc = *(const float4*)(xl + (size_t)((unsigned)s_cur*OUTP_ + (sub<<2)));
    for (int j = 0; j < m; j += 4){
      int s_next = __shfl(pv, (j + 4 + slot) & 63);
      float4 xn = *(const float4*)(xl + (size_t)((unsigned)s_next*OUTP_ + (sub<<2)));
      float v0 = xc.x + r.x, v1 = xc.y + r.y, v2 = xc.z + r.z, v3 = xc.w + r.w;
      float p;
      p = fmaf(a.x, fmaf(NEG_, fminf(v0,0.f), fmaxf(v0,0.f)), 0.f);
      p = fmaf(a.y, fmaf(NEG_, fminf(v1,0.f), fmaxf(v1,0.f)), p);
      p = fmaf(a.z, fmaf(NEG_, fminf(v2,0.f), fmaxf(v2,0.f)), p);
      p = fmaf(a.w, fmaf(NEG_, fminf(v3,0.f), fmaxf(v3,0.f)), p);
      p += __shfl_xor(p, 1);
      p += __shfl_xor(p, 2);
      p += __shfl_xor(p, 4);
      p += __shfl_xor(p, 8);
      float ex = __expf(p);
      ex = (j + slot < m) ? ex : 0.f;
      den += ex;
      acc.x = fmaf(ex, xc.x, acc.x); acc.y = fmaf(ex, xc.y, acc.y);
      acc.z = fmaf(ex, xc.z, acc.z); acc.w = fmaf(ex, xc.w, acc.w);
      xc = xn;
    }
  }
  den += __shfl_xor(den, 16); den += __shfl_xor(den, 32);
  acc.x += __shfl_xor(acc.x, 16); acc.x += __shfl_xor(acc.x, 32);
  acc.y += __shfl_xor(acc.y, 16); acc.y += __shfl_xor(acc.y, 32);
  acc.z += __shfl_xor(acc.z, 16); acc.z += __shfl_xor(acc.z, 32);
  acc.w += __shfl_xor(acc.w, 16); acc.w += __shfl_xor(acc.w, 32);

  float w = 1.f / (den + 1e-16f);
  float4 b = realc ? *(const float4*)(bias + (sub<<2)) : make_float4(0,0,0,0);
  float v0 = fmaf(acc.x, w, b.x), v1 = fmaf(acc.y, w, b.y);
  float v2 = fmaf(acc.z, w, b.z), v3 = fmaf(acc.w, w, b.w);

  float mx = realc ? fmaxf(fmaxf(v0, v1), fmaxf(v2, v3)) : -3.0e38f;
  mx = fmaxf(mx, __shfl_xor(mx, 1)); mx = fmaxf(mx, __shfl_xor(mx, 2));
  mx = fmaxf(mx, __shfl_xor(mx, 4)); mx = fmaxf(mx, __shfl_xor(mx, 8));
  float es = realc ? (__expf(v0-mx) + __expf(v1-mx) + __expf(v2-mx) + __expf(v3-mx)) : 0.f;
  es += __shfl_xor(es, 1); es += __shfl_xor(es, 2);
  es += __shfl_xor(es, 4); es += __shfl_xor(es, 8);
  float ls = __logf(es);
  if (slot == 0 && realc){
    float4 o = make_float4(v0-mx-ls, v1-mx-ls, v2-mx-ls, v3-mx-ls);
    *(float4*)(out + (size_t)node*OUT_ + (sub<<2)) = o;
  }
}

extern "C" void kernel_launch(void* const* d_in, const int* in_sizes, int n_in,
                              void* d_out, int out_size, void* d_ws, size_t ws_size,
                              hipStream_t stream)
{
  const float* x    = (const float*)d_in[0];
  const float* Wl1  = (const float*)d_in[1];
  const float* bl1  = (const float*)d_in[2];
  const float* Wr1  = (const float*)d_in[3];
  const float* br1  = (const float*)d_in[4];
  const float* att1 = (const float*)d_in[5];
  const float* bias1= (const float*)d_in[6];
  const float* Wl2  = (const float*)d_in[7];
  const float* bl2  = (const float*)d_in[8];
  const float* Wr2  = (const float*)d_in[9];
  const float* br2  = (const float*)d_in[10];
  const float* att2 = (const float*)d_in[11];
  const float* bias2= (const float*)d_in[12];
  const int* src1 = (const int*)d_in[13];
  const int* dst1 = (const int*)d_in[14];
  const int* src2 = (const int*)d_in[15];
  const int* dst2 = (const int*)d_in[16];
  const int E1 = in_sizes[13];
  const int E2 = in_sizes[15];
  (void)n_in; (void)out_size; (void)ws_size;

  // ---- workspace layout (bytes), total ~275.5 MB ----
  char* ws = (char*)d_ws;
  unsigned short* xl1  = (unsigned short*)(ws + 0LL);          // bf16 [320000][256]
  unsigned short* xr1  = (unsigned short*)(ws + 163840000LL);  // bf16 [ 80000][256]
  unsigned short* hbuf = (unsigned short*)(ws + 204800000LL);  // bf16 [ 80000][256]
  float* xl2p   = (float*)(ws + 245760000LL);                  // f32  [ 80000][64] padded
  float* xr2p   = (float*)(ws + 266240000LL);                  // f32  [ 16000][64] padded
  int*   perm1  = (int*)  (ws + 270336000LL);                  // int  [800000]
  int*   perm2  = (int*)  (ws + 273536000LL);                  // int  [160000]
  int*   cnt1   = (int*)  (ws + 274176000LL);                  // int  [ 80000] (zeroed)
  int*   cnt2   = (int*)  (ws + 274496000LL);                  // int  [ 16000] (zeroed)
  int*   off1   = (int*)  (ws + 274560000LL);                  // int  [ 80000]
  int*   cur1   = (int*)  (ws + 274880000LL);                  // int  [ 80000]
  int*   off2   = (int*)  (ws + 275200000LL);                  // int  [ 16000]
  int*   cur2   = (int*)  (ws + 275264000LL);                  // int  [ 16000]
  int*   part1  = (int*)  (ws + 275328000LL);                  // int  [   512]
  int*   part2  = (int*)  (ws + 275330048LL);                  // int  [   512]
  unsigned short* Wt1l = (unsigned short*)(ws + 275332096LL);  // bf16 [256][128]
  unsigned short* Wt1r = (unsigned short*)(ws + 275397632LL);  // bf16 [256][128]
  unsigned short* Wt2l = (unsigned short*)(ws + 275463168LL);  // bf16 [ 48][256]
  unsigned short* Wt2r = (unsigned short*)(ws + 275487744LL);  // bf16 [ 48][256]

  hipMemsetAsync(ws + 274176000LL, 0, 384000LL, stream);       // cnt1 + cnt2

  const int nb1 = (N1_ + 255) / 256;   // 313
  const int nb2 = (N2_ + 255) / 256;   // 63

  transpose_all<<<352, 256, 0, stream>>>(Wl1, Wr1, Wl2, Wr2, Wt1l, Wt1r, Wt2l, Wt2r);

  // CSR build for both edge sets (independent of GEMMs)
  hist_both         <<<(E1+E2+255)/256, 256, 0, stream>>>(dst1, dst2, cnt1, cnt2, E1, E2);
  scan_local_both   <<<nb1+nb2, 256, 0, stream>>>(cnt1, cnt2, off1, off2, part1, part2, N1_, N2_, nb1);
  scan_partials_both<<<2, 512, 0, stream>>>(part1, part2, nb1, nb2);
  scan_finalize_both<<<nb1+nb2, 256, 0, stream>>>(off1, off2, part1, part2, cur1, cur2, N1_, N2_, nb1);
  scatter_both      <<<(E1+E2+255)/256, 256, 0, stream>>>(src1, dst1, src2, dst2,
                                                          cur1, cur2, perm1, perm2, E1, E2);

  gemm1_split<<<N0_/64 + N1_/64, 256, 0, stream>>>(x, Wt1l, Wt1r, bl1, br1, xl1, xr1, N0_/64);

  gat_aggregate1<<<(N1_+3)/4, 256, 0, stream>>>(xl1, xr1, off1, cnt1, perm1,
                                                att1, bias1, hbuf, N1_);

  gemm2_split<<<N1_/64 + N2_/64, 256, 0, stream>>>(hbuf, Wt2l, Wt2r, bl2, br2, xl2p, xr2p, N1_/64);

  gat_aggregate2<<<(N2_+3)/4, 256, 0, stream>>>(xl2p, xr2p, off2, cnt2, perm2,
                                                att2, bias2, (float*)d_out, N2_);
}